// Round 1
// baseline (1686.513 us; speedup 1.0000x reference)
//
#include <hip/hip_runtime.h>
#include <stdint.h>
#include <stddef.h>

typedef _Float16 f16;
typedef _Float16 f16x8 __attribute__((ext_vector_type(8)));
typedef float    f32x4 __attribute__((ext_vector_type(4)));

#define NB    16384   // batch
#define TT    100     // encoder steps
#define II    6       // input features
#define HH    128     // hidden
#define OLEN  20      // decoder steps
#define OO    2       // output features
#define RR    64      // batch rows per block

// f16-element offsets into workspace (8 recurrent mats are [512][128] = 65536 f16)
#define OFF_WHH0   0
#define OFF_WIH1   65536
#define OFF_WHH1   131072
#define OFF_DWIH0  196608
#define OFF_DWHH0  262144
#define OFF_DWIH1  327680
#define OFF_DWHH1  393216
#define OFF_WIH0P  458752          // [512][8] zero-padded (K=6 -> 8), prescaled
#define OFF_FCW    462848          // [2][128], NOT prescaled
#define OFF_BIAS_B 926208          // byte offset: 4*512 f32 combined prescaled biases
#define WS_BYTES   934400

#define SWZ(r) (((r) & 15) << 3)   // f16-unit XOR swizzle for h tiles

__device__ __forceinline__ float exp2_(float x) {
#if __has_builtin(__builtin_amdgcn_exp2f)
    return __builtin_amdgcn_exp2f(x);
#else
    return exp2f(x);
#endif
}
__device__ __forceinline__ float rcp_(float x) {
#if __has_builtin(__builtin_amdgcn_rcpf)
    return __builtin_amdgcn_rcpf(x);
#else
    return 1.f / x;
#endif
}

// ---------------- weight prep: fp32 -> f16, gate-prescaled; fuse+prescale biases ----
// gate rows (i,f,o) scaled by -log2(e) so sigmoid(z) = rcp(1+exp2(u));
// gate rows (g)     scaled by 2*log2(e) so tanh(z) = 1 - 2*rcp(1+exp2(u)).
__global__ __launch_bounds__(256) void prep_kernel(
    const float* eWih0, const float* eWhh0, const float* eWih1, const float* eWhh1,
    const float* dWih0, const float* dWhh0, const float* dWih1, const float* dWhh1,
    const float* ebi0,  const float* ebh0,  const float* ebi1,  const float* ebh1,
    const float* dbi0,  const float* dbh0,  const float* dbi1,  const float* dbh1,
    const float* fcW,   f16* w16, float* bws)
{
    const float GS0 = -1.4426950408889634f;   // i, f, o
    const float GS2 =  2.8853900817779268f;   // g
    int i0 = blockIdx.x * blockDim.x + threadIdx.x;
    int stride = gridDim.x * blockDim.x;
    const float* srcs[7] = {eWhh0, eWih1, eWhh1, dWih0, dWhh0, dWih1, dWhh1};
    for (int i = i0; i < 7 * 65536; i += stride) {
        int rem = i & 65535;
        float s = ((rem >> 14) == 2) ? GS2 : GS0;
        w16[i] = (f16)(srcs[i >> 16][rem] * s);
    }
    for (int i = i0; i < 512 * 8; i += stride) {
        int n = i >> 3, k = i & 7;
        float s = ((n >> 7) == 2) ? GS2 : GS0;
        w16[OFF_WIH0P + i] = (k < II) ? (f16)(eWih0[n * II + k] * s) : (f16)0.f;
    }
    for (int i = i0; i < OO * HH; i += stride) w16[OFF_FCW + i] = (f16)fcW[i];
    const float* bia[4] = {ebi0, ebi1, dbi0, dbi1};
    const float* bib[4] = {ebh0, ebh1, dbh0, dbh1};
    for (int i = i0; i < 4 * 512; i += stride) {
        int j = i & 511;
        float s = ((j >> 7) == 2) ? GS2 : GS0;
        bws[i] = (bia[i >> 9][j] + bib[i >> 9][j]) * s;
    }
}

// ---------------- main persistent LSTM kernel: 1 block = 64 batch rows ----------------
// R13/R14 structure (short-lived streamed banks, dbuf h, per-thread-LDS c):
// traffic-clean (FETCH 24MB, WRITE 2.5MB, no spills). R16 pipelined the
// RECURRENCE: phaseB(t-1) has no dependency on phaseA(t) (both consume only
// pre-region values: h0(t-1), h1(t-2) via parity-[p] buffers), so one region
// computes BOTH with ONE barrier.
// R17: ANTI-PHASE WAVES. Counter analysis showed region time ~= the SERIAL SUM
// of pipe times (MFMA 8.1K + trans 5.1K + VALU 2.7K + VMEM 6-12K cyc/SIMD
// ~= 30K measured) because both waves on a SIMD are phase-locked: same
// instruction class at the same moment, no cross-pipe overlap (m114: overlap
// needs waves in different phases). Since phaseA(t) and phaseB(t-1) are
// order-independent per wave (all reads [p], all writes disjoint [p^1] +
// per-thread c slots), half the waves now run B-then-A. Checkerboard parity
// (w ^ (w>>2)) & 1 puts one A-first and one B-first wave on each SIMD under
// BOTH plausible wave->SIMD mappings (w%4 round-robin and w>>1 pairing), so
// one wave's MFMA stream overlaps the partner's act-transcendentals and L2
// weight bursts. Zero extra registers; decoder (truly serial) unchanged.
__global__ __launch_bounds__(512, 2) void lstm_kernel(
    const float* __restrict__ xg, const f16* __restrict__ wsf,
    const float* __restrict__ bws, const float* __restrict__ fcb,
    float* __restrict__ out)
{
    __shared__ __align__(16) f16 h0s[2][RR][HH];     // 32KB, XOR-swizzled
    __shared__ __align__(16) f16 h1s[2][RR][HH];     // 32KB
    __shared__ __align__(16) f16 xs[2][RR][8];       // 2KB
    __shared__ __align__(16) f16 fcws[OO * HH];      // .5KB
    __shared__ float bias_s[4 * 512];                // 8KB
    __shared__ f32x4 c0s[4][512];                    // 32KB cell-0 state (per-thread slots)
    __shared__ f32x4 c1s[4][512];                    // 32KB cell-1 state -> 138.5KB

    const int tid = threadIdx.x;
    const int w   = tid >> 6;      // wave 0..7 -> hidden cols 16w..16w+15
    const int ln  = tid & 63;
    const int l15 = ln & 15;
    const int lg  = ln >> 4;       // lane k-group
    const int r0  = blockIdx.x * RR;
    // anti-phase parity: one of each per SIMD under w%4 AND w>>1 pairings
    const int bfirst = (w ^ (w >> 2)) & 1;

    // ---- init LDS (note: BOTH h1 buffers zeroed -- region 1 reads h1s[1] as h1(-1))
    for (int i = tid; i < OO * HH; i += 512) fcws[i] = wsf[OFF_FCW + i];
    for (int i = tid; i < 4 * 512; i += 512) bias_s[i] = bws[i];
    for (int i = tid; i < RR * HH; i += 512) {
        h0s[0][0][i] = (f16)0.f;
        h1s[0][0][i] = (f16)0.f;
        h1s[1][0][i] = (f16)0.f;
    }
    {
        const f32x4 z4 = {0.f, 0.f, 0.f, 0.f};
        for (int i = tid; i < 4 * 512; i += 512) {
            (&c0s[0][0])[i] = z4;
            (&c1s[0][0])[i] = z4;
        }
    }
    {   // stage x[t=0]
        int r = tid >> 3, k = tid & 7;
        float v = (k < II) ? xg[((size_t)(r0 + r) * TT + 0) * II + k] : 0.f;
        xs[0][r][k] = (f16)v;
    }

    f32x4 acc[4][4];   // [gate][m] accumulators (64 regs, MFMA C/D; reused A->B)
    f16x8 bank[4][4];  // [gate][kk] streamed B bank (64 regs, short-lived)
    f16x8 bX[4];       // encoder x-weights (8 regs; zero in lanes lg>0)

    {
        const f16x8 z = {};
        #pragma unroll
        for (int g = 0; g < 4; ++g) {
            const int nt = (g << 3) + w;
            bX[g] = (lg == 0)
                ? *(const f16x8*)(wsf + OFF_WIH0P + (size_t)((nt << 4) + l15) * 8)
                : z;
        }
    }

    // stream one matrix's B-fragments into the bank, kk-major (pipeline-friendly:
    // the consuming kR's kk=0 MFMAs depend only on the first 4 loads). Offset is
    // tied through an empty asm so the loads re-execute per call (no hoisting
    // into a persistent spill-prone set -- the R5-R11 failure mode).
    auto loadBank = [&](unsigned offElems) {
        unsigned off = offElems;
        asm volatile("" : "+v"(off));
        const f16* W = wsf + off;
        #pragma unroll
        for (int kk = 0; kk < 4; ++kk)
            #pragma unroll
            for (int g = 0; g < 4; ++g) {
                const int nt = (g << 3) + w;
                bank[g][kk] = *(const f16x8*)(W + (size_t)((nt << 4) + l15) * HH + (kk << 5) + (lg << 3));
            }
    };
    // fence + load: sched_barrier stops the new bank's loads from hoisting into
    // the previous bank's MFMA region (which would double bank liveness).
    #define LB(off) do { __builtin_amdgcn_sched_barrier(0); loadBank(off); } while (0)

    auto zacc = [&](int cell) {
        #pragma unroll
        for (int g = 0; g < 4; ++g) {
            float b = bias_s[(cell << 9) | (g << 7) | (w << 4) | l15];
            f32x4 b4 = {b, b, b, b};
            #pragma unroll
            for (int m = 0; m < 4; ++m) acc[g][m] = b4;
        }
    };

    // one K=128 GEMM over ALL m-tiles with the current bank (kk-major)
    auto kR = [&](const f16* hsrc) {
        #pragma unroll
        for (int kk = 0; kk < 4; ++kk)
            #pragma unroll
            for (int m = 0; m < 4; ++m) {
                int r = (m << 4) + l15;
                int c = ((kk << 5) | (lg << 3)) ^ SWZ(r);
                f16x8 a = *(const f16x8*)(hsrc + (size_t)r * HH + c);
                #pragma unroll
                for (int g = 0; g < 4; ++g)
                    acc[g][m] = __builtin_amdgcn_mfma_f32_16x16x32_f16(a, bank[g][kk], acc[g][m], 0, 0, 0);
            }
    };

    // encoder x-term: zero-padded K=32 MFMA (real K=6 in lanes lg==0); no bank dep
    auto mfx = [&](const f16 (*xsrc)[8]) {
        const f16x8 z = {};
        #pragma unroll
        for (int m = 0; m < 4; ++m) {
            int r = (m << 4) + l15;
            f16x8 a = lg ? z : *(const f16x8*)(&xsrc[r][0]);
            #pragma unroll
            for (int g = 0; g < 4; ++g)
                acc[g][m] = __builtin_amdgcn_mfma_f32_16x16x32_f16(a, bX[g], acc[g][m], 0, 0, 0);
        }
    };

    // gate nonlinearities; c in per-thread LDS slots; h -> hdst (parity-[p^1]
    // buffer, never read in the same region -> race-free).
    auto act = [&](f32x4 (*cs)[512], f16* hdst) {
        const int col = (w << 4) + l15;
        #pragma unroll
        for (int m = 0; m < 4; ++m) {
            f32x4 cold = cs[m][tid];
            f32x4 cnew;
            #pragma unroll
            for (int q = 0; q < 4; ++q) {
                float si = rcp_(1.f + exp2_(acc[0][m][q]));
                float sf = rcp_(1.f + exp2_(acc[1][m][q]));
                float tg = 1.f - 2.f * rcp_(1.f + exp2_(acc[2][m][q]));
                float so = rcp_(1.f + exp2_(acc[3][m][q]));
                float cn = sf * cold[q] + si * tg;
                cnew[q] = cn;
                float hn = so * (1.f - 2.f * rcp_(1.f + exp2_(2.8853900817779268f * cn)));
                int r = (m << 4) + (lg << 2) + q;
                hdst[(size_t)r * HH + (col ^ SWZ(r))] = (f16)hn;
            }
            cs[m][tid] = cnew;
        }
    };

    __syncthreads();   // init visible

    // ============ encoder: 100 pipelined regions + tail, 1 barrier each ============
    // region t: phaseA(t):  gates0 = b0 + x(t)*Wih0 + h0s[p]*Whh0 -> h0s[p^1], c0
    //           phaseB(t-1):gates1 = b1 + h1s[p]*Whh1 + h0s[p]*Wih1 -> h1s[p^1], c1
    // (h0(t-1) lives in h0s[p]; h1(t-2) in h1s[p] -- all reads pre-region.)
    // Per-wave phase ORDER is free (phases fully independent) -> anti-phase arms.
    for (int t = 0; t < TT; ++t) {
        const int p = t & 1;
        float xv = 0.f;
        if (t + 1 < TT && (tid & 7) < II)
            xv = xg[((size_t)(r0 + (tid >> 3)) * TT + (t + 1)) * II + (tid & 7)];
        if (!bfirst) {
            // ---- arm 0: A(t) then B(t-1)
            LB(OFF_WHH0);
            zacc(0);
            mfx(xs[p]);                      // runs under WHH0 burst
            kR(&h0s[p][0][0]);
            LB(OFF_WHH1);                    // issue next burst...
            act(c0s, &h0s[p ^ 1][0][0]);     // ...hidden under act0's trans/VALU
            if (t > 0) {
                zacc(1);
                kR(&h1s[p][0][0]);           // state term: h1(t-2)
                LB(OFF_WIH1);
                kR(&h0s[p][0][0]);           // input term: h0(t-1) (OLD buffer)
                act(c1s, &h1s[p ^ 1][0][0]); // h1(t-1)
            }
        } else {
            // ---- arm 1: B(t-1) then A(t) (same work, opposite pipe phase)
            if (t > 0) {
                LB(OFF_WHH1);
                zacc(1);
                kR(&h1s[p][0][0]);           // state term: h1(t-2)
                LB(OFF_WIH1);
                kR(&h0s[p][0][0]);           // input term: h0(t-1)
                LB(OFF_WHH0);                // WHH0 burst flies under act1
                act(c1s, &h1s[p ^ 1][0][0]); // h1(t-1)
                zacc(0);
                mfx(xs[p]);
                kR(&h0s[p][0][0]);
                act(c0s, &h0s[p ^ 1][0][0]);
            } else {
                LB(OFF_WHH0);
                zacc(0);
                mfx(xs[p]);
                kR(&h0s[p][0][0]);
                act(c0s, &h0s[p ^ 1][0][0]);
            }
        }
        if (t + 1 < TT) xs[p ^ 1][tid >> 3][tid & 7] = (f16)xv;
        __builtin_amdgcn_sched_barrier(0);
        __syncthreads();                 // ONE barrier per region (all waves reach it)
    }
    // tail region: phaseB(99). After loop: h0(99)=h0s[0], h1(98)=h1s[0].
    {
        LB(OFF_WHH1);
        zacc(1);
        kR(&h1s[0][0][0]);               // h1(98)
        LB(OFF_WIH1);
        kR(&h0s[0][0][0]);               // h0(99)
        act(c1s, &h1s[1][0][0]);         // h1(99) -> h1s[1]
        __builtin_amdgcn_sched_barrier(0);
        __syncthreads();
    }
    // decoder entry: h0 cur = h0s[0], h1 cur = h1s[1]

    float fb = (tid < RR * OO) ? fcb[tid & 1] : 0.f;

    // ============ decoder: 20 steps, 2 barriers/step ============
    // step s (q=s&1): reads h0s[q], h1s[q^1]; writes h0s[q^1] (A), h1s[q] (B).
    // Strictly serial (B(s) needs A(s)'s h0 through the barrier) -> no anti-phase.
    for (int s = 0; s < OLEN; ++s) {
        const int q = s & 1;
        // Phase A: gates2 = b2 + h0d(s-1)*DWhh0 + h1d(s-1)*DWih0 -> h0d(s)
        LB(OFF_DWHH0);
        zacc(2);
        kR(&h0s[q][0][0]);
        LB(OFF_DWIH0);
        kR(&h1s[q ^ 1][0][0]);
        act(c0s, &h0s[q ^ 1][0][0]);
        __builtin_amdgcn_sched_barrier(0);
        __syncthreads();                 // BAR1: h0d(s) published
        // Phase B: gates3 = b3 + h1d(s-1)*DWhh1 + h0d(s)*DWih1 -> h1d(s)
        LB(OFF_DWHH1);
        zacc(3);
        kR(&h1s[q ^ 1][0][0]);
        LB(OFF_DWIH1);
        kR(&h0s[q ^ 1][0][0]);
        act(c1s, &h1s[q][0][0]);
        __builtin_amdgcn_sched_barrier(0);
        __syncthreads();                 // BAR2: h1d(s) published
        // fc: pred[r][o] = h1d(s) . fc_W[o] + fc_b[o]  (threads 0..127)
        if (tid < RR * OO) {
            int r = tid >> 1, o = tid & 1;
            float a = fb;
            const f16* hrow = &h1s[q][r][0];
            #pragma unroll
            for (int ccol = 0; ccol < HH; ccol += 8) {
                int csw = ccol ^ SWZ(r);
                f16x8 hv = *(const f16x8*)(hrow + csw);
                f16x8 wv = *(const f16x8*)(&fcws[o * HH + ccol]);
                #pragma unroll
                for (int j = 0; j < 8; ++j) a += (float)hv[j] * (float)wv[j];
            }
            out[((size_t)(r0 + r) * OLEN + s) * OO + o] = a;
        }
    }
    #undef LB
}

extern "C" void kernel_launch(void* const* d_in, const int* in_sizes, int n_in,
                              void* d_out, int out_size, void* d_ws, size_t ws_size,
                              hipStream_t stream) {
    const float* x     = (const float*)d_in[0];
    const float* eWih0 = (const float*)d_in[1];
    const float* eWhh0 = (const float*)d_in[2];
    const float* ebi0  = (const float*)d_in[3];
    const float* ebh0  = (const float*)d_in[4];
    const float* eWih1 = (const float*)d_in[5];
    const float* eWhh1 = (const float*)d_in[6];
    const float* ebi1  = (const float*)d_in[7];
    const float* ebh1  = (const float*)d_in[8];
    const float* dWih0 = (const float*)d_in[9];
    const float* dWhh0 = (const float*)d_in[10];
    const float* dbi0  = (const float*)d_in[11];
    const float* dbh0  = (const float*)d_in[12];
    const float* dWih1 = (const float*)d_in[13];
    const float* dWhh1 = (const float*)d_in[14];
    const float* dbi1  = (const float*)d_in[15];
    const float* dbh1  = (const float*)d_in[16];
    const float* fcW   = (const float*)d_in[17];
    const float* fcb   = (const float*)d_in[18];

    f16*   w16 = (f16*)d_ws;
    float* bws = (float*)((char*)d_ws + OFF_BIAS_B);

    prep_kernel<<<256, 256, 0, stream>>>(eWih0, eWhh0, eWih1, eWhh1,
                                         dWih0, dWhh0, dWih1, dWhh1,
                                         ebi0, ebh0, ebi1, ebh1,
                                         dbi0, dbh0, dbi1, dbh1,
                                         fcW, w16, bws);
    lstm_kernel<<<NB / RR, 512, 0, stream>>>(x, w16, bws, fcb, (float*)d_out);
}